// Round 7
// baseline (2386.600 us; speedup 1.0000x reference)
//
#include <hip/hip_runtime.h>
#include <hip/hip_bf16.h>

#define EPS 1e-5f
#define Bn 8
#define Cn 512
#define Nn 2304
#define C1n 256
#define C2n 256
#define CGn 128

typedef __bf16 bf16_t;
typedef __bf16 bf16x8 __attribute__((ext_vector_type(8)));
typedef float f32x4 __attribute__((ext_vector_type(4)));

#define MFMA16(a, b, c) __builtin_amdgcn_mfma_f32_16x16x32_bf16(a, b, c, 0, 0, 0)

// ---------- WPAR element offsets (bf16 weight arena) ----------
static constexpr size_t P_TW = 0;            // (4,256,512)
static constexpr size_t P_TB = 524288;
static constexpr size_t P_PW = 525312;
static constexpr size_t P_PB = 1049600;
static constexpr size_t P_GW = 1050624;
static constexpr size_t P_GB = 1574912;
static constexpr size_t P_WW = 1575936;      // (4,128,256)
static constexpr size_t P_WB = 1707008;
static constexpr size_t P_WG = 1707520;
static constexpr size_t P_WBE = 1708032;
static constexpr size_t P_BCW = 1708544;     // (512,1024)
static constexpr size_t P_BCB = 2232832;
static constexpr size_t P_BCG = 2233344;
static constexpr size_t P_BCBE = 2233856;

// ---------- workspace layout (bytes); peak 80.0 MB (proven safe: 98.9 MB ran) ----------
static constexpr size_t OFF_WPAR  = 0;          // 4,468,736
static constexpr size_t OFF_BIASF = 4468736;
static constexpr size_t OFF_SW    = 4470784;
static constexpr size_t OFF_TW2   = 4472832;
static constexpr size_t OFF_SO    = 4474880;
static constexpr size_t OFF_TO    = 4476928;
static constexpr size_t OFF_STATW = 4478976;    // f64[1024] (memset w/ STATO)
static constexpr size_t OFF_STATO = 4487168;    // f64[1024]
static constexpr size_t OFF_WY    = 4495360;    // bf16 (B,N,512) 18,874,368
static constexpr size_t OFF_ARENA = 23369728;   // 16 slots x (Q+K+V); bcwF overlay
static constexpr size_t QS  = 589824;           // elems: 2304*256
static constexpr size_t SL3 = 3 * QS;           // elems per slot (Q,K,V)
// end = 23,369,728 + 16*3*1,179,648 = 79,992,832

// ---------- K0: convert 14 f32 weight inputs -> bf16 WPAR ----------
struct WArgs {
  const float* src[14];
  unsigned n[14];
  unsigned off[14];
};

__global__ __launch_bounds__(256) void k_wconv(WArgs a, bf16_t* __restrict__ par) {
  int which = blockIdx.y;
  const float* s = a.src[which];
  unsigned n = a.n[which];
  bf16_t* dst = par + a.off[which];
  size_t stride = (size_t)gridDim.x * blockDim.x;
  for (size_t i = (size_t)blockIdx.x * blockDim.x + threadIdx.x; i < n; i += stride)
    dst[i] = (bf16_t)s[i];
}

// ---------- K1a: theta/phi projection -> Q or K slot (N,256) ----------
// grid (36, 4, 2*cnt): z = s*2 + which (0=theta->Q, 1=phi->K)
__global__ __launch_bounds__(256) void k_proj_qk(
    const float* __restrict__ feats, const bf16_t* __restrict__ par,
    bf16_t* __restrict__ arena, int gb_base) {
  __shared__ alignas(16) bf16_t xsT[64][40];
  int z = blockIdx.z, s = z >> 1, p = z & 1;
  int gb = gb_base + s, g = gb >> 3, b = gb & 7;
  const bf16_t* W = par + (p == 0 ? P_TW : P_PW) + (size_t)g * C1n * Cn;
  const bf16_t* bias = par + (p == 0 ? P_TB : P_PB) + g * C1n;
  bf16_t* out = arena + (size_t)s * SL3 + (size_t)p * QS;

  int tid = threadIdx.x, w = tid >> 6, lane = tid & 63;
  int l15 = lane & 15, quad = lane >> 4;
  int m0 = blockIdx.x * 64;
  int o0 = blockIdx.y * 64;

  f32x4 acc[4];
#pragma unroll
  for (int j = 0; j < 4; j++) acc[j] = (f32x4){0.f, 0.f, 0.f, 0.f};

  for (int kk = 0; kk < 16; kk++) {
    int c0 = kk * 32;
    __syncthreads();
#pragma unroll
    for (int i = 0; i < 8; i++) {
      int cc = i * 4 + w;
      xsT[lane][cc] = (bf16_t)feats[((size_t)b * Cn + c0 + cc) * Nn + m0 + lane];
    }
    __syncthreads();
    bf16x8 a = *(const bf16x8*)(&xsT[w * 16 + l15][quad * 8]);
#pragma unroll
    for (int j = 0; j < 4; j++) {
      bf16x8 bw = *(const bf16x8*)(W + (size_t)(o0 + j * 16 + l15) * Cn + c0 + quad * 8);
      acc[j] = MFMA16(a, bw, acc[j]);
    }
  }
#pragma unroll
  for (int j = 0; j < 4; j++) {
    int col = o0 + j * 16 + l15;
    float bv = (float)bias[col];
#pragma unroll
    for (int r = 0; r < 4; r++)
      out[(size_t)(m0 + w * 16 + quad * 4 + r) * C1n + col] = (bf16_t)(acc[j][r] + bv);
  }
}

// ---------- K1b: g projection -> V slot (256,N) ----------
__global__ __launch_bounds__(256) void k_proj_v(
    const float* __restrict__ feats, const bf16_t* __restrict__ par,
    bf16_t* __restrict__ arena, int gb_base) {
  __shared__ alignas(16) bf16_t xsT[64][40];
  int s = blockIdx.z, gb = gb_base + s, g = gb >> 3, b = gb & 7;
  const bf16_t* W = par + P_GW + (size_t)g * C2n * Cn;
  const bf16_t* bias = par + P_GB + g * C2n;
  bf16_t* out = arena + (size_t)s * SL3 + 2 * QS;

  int tid = threadIdx.x, w = tid >> 6, lane = tid & 63;
  int l15 = lane & 15, quad = lane >> 4;
  int n0 = blockIdx.x * 64;
  int c20 = blockIdx.y * 64 + w * 16;

  f32x4 acc[4];
#pragma unroll
  for (int j = 0; j < 4; j++) acc[j] = (f32x4){0.f, 0.f, 0.f, 0.f};

  for (int kk = 0; kk < 16; kk++) {
    int c0 = kk * 32;
    __syncthreads();
#pragma unroll
    for (int i = 0; i < 8; i++) {
      int cc = i * 4 + w;
      xsT[lane][cc] = (bf16_t)feats[((size_t)b * Cn + c0 + cc) * Nn + n0 + lane];
    }
    __syncthreads();
    bf16x8 a = *(const bf16x8*)(W + (size_t)(c20 + l15) * Cn + c0 + quad * 8);
#pragma unroll
    for (int j = 0; j < 4; j++) {
      bf16x8 bx = *(const bf16x8*)(&xsT[j * 16 + l15][quad * 8]);
      acc[j] = MFMA16(a, bx, acc[j]);
    }
  }
#pragma unroll
  for (int r = 0; r < 4; r++) {
    int row = c20 + quad * 4 + r;
    float bv = (float)bias[row];
#pragma unroll
    for (int j = 0; j < 4; j++)
      out[(size_t)row * Nn + n0 + j * 16 + l15] = (bf16_t)(acc[j][r] + bv);
  }
}

// ---------- K2: attention (unnormalized-exp flash) + fused W-conv ----------
// block = 4 waves x 16 Q-rows; each wave loops full N; l via ones-MFMA.
__global__ __launch_bounds__(256) void k_attn_wy(
    const bf16_t* __restrict__ arena, const bf16_t* __restrict__ par,
    bf16_t* __restrict__ wyBF, int gb_base) {
  __shared__ alignas(16) bf16_t pbuf[4][16 * 40];   // 5120 B
  __shared__ alignas(16) bf16_t ybuf[4][16 * 264];  // 33792 B
  int s = blockIdx.y, gb = gb_base + s, g = gb >> 3, b = gb & 7;
  const bf16_t* Qp = arena + (size_t)s * SL3;
  const bf16_t* Kp = Qp + QS;
  const bf16_t* Vp = Qp + 2 * QS;

  int tid = threadIdx.x, w = tid >> 6, lane = tid & 63;
  int l15 = lane & 15, quad = lane >> 4;
  int m0 = blockIdx.x * 64 + w * 16;

  bf16x8 qf[8];
  const bf16_t* qrow = Qp + (size_t)(m0 + l15) * C1n + quad * 8;
#pragma unroll
  for (int kk = 0; kk < 8; kk++) qf[kk] = *(const bf16x8*)(qrow + kk * 32);

  f32x4 oacc[16];
#pragma unroll
  for (int ct = 0; ct < 16; ct++) oacc[ct] = (f32x4){0.f, 0.f, 0.f, 0.f};
  f32x4 lacc = (f32x4){0.f, 0.f, 0.f, 0.f};

  bf16x8 ones;
#pragma unroll
  for (int i = 0; i < 8; i++) ones[i] = (bf16_t)1.0f;

  // exp(f/16) == exp2(f * 0.0625 * log2(e))
  const float SC = 0.0625f * 1.44269504088896f;
  bf16_t* pw = pbuf[w];

  for (int n0 = 0; n0 < Nn; n0 += 32) {
    f32x4 s0 = (f32x4){0.f, 0.f, 0.f, 0.f};
    f32x4 s1 = (f32x4){0.f, 0.f, 0.f, 0.f};
    const bf16_t* k0p = Kp + (size_t)(n0 + l15) * C1n + quad * 8;
    const bf16_t* k1p = k0p + 16 * C1n;
#pragma unroll
    for (int kk = 0; kk < 8; kk++) {
      s0 = MFMA16(qf[kk], *(const bf16x8*)(k0p + kk * 32), s0);
      s1 = MFMA16(qf[kk], *(const bf16x8*)(k1p + kk * 32), s1);
    }
#pragma unroll
    for (int r = 0; r < 4; r++) {
      s0[r] = exp2f(s0[r] * SC);
      s1[r] = exp2f(s1[r] * SC);
      pw[(quad * 4 + r) * 40 + l15] = (bf16_t)s0[r];
      pw[(quad * 4 + r) * 40 + 16 + l15] = (bf16_t)s1[r];
    }
    bf16x8 pa = *(const bf16x8*)(pw + l15 * 40 + quad * 8);
    lacc = MFMA16(pa, ones, lacc);  // row-sums of exp, free l accumulation
    const bf16_t* vbase = Vp + (size_t)l15 * Nn + n0 + quad * 8;
#pragma unroll
    for (int ct = 0; ct < 16; ct++) {
      bf16x8 vb = *(const bf16x8*)(vbase + (size_t)ct * 16 * Nn);
      oacc[ct] = MFMA16(pa, vb, oacc[ct]);
    }
  }

  float inv[4];
#pragma unroll
  for (int r = 0; r < 4; r++) inv[r] = 1.f / lacc[r];

  // y -> LDS A-layout (per-wave; DS in-order per wave, no sync needed)
  bf16_t* yb = ybuf[w];
#pragma unroll
  for (int ct = 0; ct < 16; ct++)
#pragma unroll
    for (int r = 0; r < 4; r++)
      yb[(quad * 4 + r) * 264 + ct * 16 + l15] = (bf16_t)(oacc[ct][r] * inv[r]);

  // fused W-conv: wy[m][o] = sum_c y[m][c] w_w[o][c]
  const bf16_t* Wg = par + P_WW + (size_t)g * CGn * C2n;
  const bf16_t* wbias = par + P_WB + g * CGn;
  f32x4 wyacc[8];
#pragma unroll
  for (int j = 0; j < 8; j++) wyacc[j] = (f32x4){0.f, 0.f, 0.f, 0.f};
#pragma unroll
  for (int kk = 0; kk < 8; kk++) {
    bf16x8 ya = *(const bf16x8*)(yb + l15 * 264 + kk * 32 + quad * 8);
#pragma unroll
    for (int j = 0; j < 8; j++) {
      bf16x8 wv = *(const bf16x8*)(Wg + (size_t)(j * 16 + l15) * C2n + kk * 32 + quad * 8);
      wyacc[j] = MFMA16(ya, wv, wyacc[j]);
    }
  }
#pragma unroll
  for (int j = 0; j < 8; j++) {
    int o = j * 16 + l15;
    float bv = (float)wbias[o];
#pragma unroll
    for (int r = 0; r < 4; r++)
      wyBF[((size_t)b * Nn + m0 + quad * 4 + r) * 512 + g * 128 + o] =
          (bf16_t)(wyacc[j][r] + bv);
  }
}

// ---------- wy BN stats (channel-last), f64 atomics ----------
__global__ __launch_bounds__(256) void k_wy_stats(const bf16_t* __restrict__ wyBF,
                                                  double* __restrict__ stats) {
  int b = blockIdx.y;
  int m0 = blockIdx.x * 64;
  int tid = threadIdx.x;
  double s0 = 0., q0 = 0., s1 = 0., q1 = 0.;
  const bf16_t* base = wyBF + ((size_t)b * Nn + m0) * 512;
  for (int i = 0; i < 64; i++) {
    double v0 = (double)(float)base[(size_t)i * 512 + tid];
    double v1 = (double)(float)base[(size_t)i * 512 + 256 + tid];
    s0 += v0; q0 += v0 * v0; s1 += v1; q1 += v1 * v1;
  }
  atomicAdd(&stats[tid], s0);
  atomicAdd(&stats[512 + tid], q0);
  atomicAdd(&stats[256 + tid], s1);
  atomicAdd(&stats[768 + tid], q1);
}

// ---------- BN scale/shift ----------
__global__ void k_bn_st(const double* __restrict__ stats, const bf16_t* __restrict__ gamma,
                        const bf16_t* __restrict__ beta, float* __restrict__ sArr,
                        float* __restrict__ tArr, double inv_count) {
  int ch = threadIdx.x;  // 512
  double mean = stats[ch] * inv_count;
  double var = stats[512 + ch] * inv_count - mean * mean;
  double s = (double)(float)gamma[ch] / sqrt(var + (double)EPS);
  sArr[ch] = (float)s;
  tArr[ch] = (float)((double)(float)beta[ch] - mean * s);
}

// ---------- fold wy-BN into bottleneck weights ----------
__global__ __launch_bounds__(256) void k_fold(
    const bf16_t* __restrict__ par, const float* __restrict__ sW,
    const float* __restrict__ tW, bf16_t* __restrict__ bcwF, float* __restrict__ biasF) {
  int oo = blockIdx.x;
  int tid = threadIdx.x;
  const bf16_t* row = par + P_BCW + (size_t)oo * 1024;
  bf16_t* orow = bcwF + (size_t)oo * 1024;
  float part = 0.f;
  for (int c = tid; c < 512; c += 256) orow[c] = row[c];
  for (int c = 512 + tid; c < 1024; c += 256) {
    float wv = (float)row[c];
    orow[c] = (bf16_t)(wv * sW[c - 512]);
    part += wv * tW[c - 512];
  }
  __shared__ float red[256];
  red[tid] = part;
  __syncthreads();
  for (int s = 128; s > 0; s >>= 1) {
    if (tid < s) red[tid] += red[tid + s];
    __syncthreads();
  }
  if (tid == 0) biasF[oo] = (float)par[P_BCB + oo] + red[0];
}

// ---------- final GEMM: mode 0 -> f64 atomic stats; mode 1 -> normalized f32 out ----------
__global__ __launch_bounds__(256) void k_final(
    const float* __restrict__ feats, const bf16_t* __restrict__ wyBF,
    const bf16_t* __restrict__ bcwF, const float* __restrict__ biasF,
    const float* __restrict__ sO, const float* __restrict__ tO,
    double* __restrict__ stats, float* __restrict__ out, int mode) {
  __shared__ alignas(16) bf16_t xsT[64][40];
  int b = blockIdx.z;
  int tid = threadIdx.x, w = tid >> 6, lane = tid & 63;
  int l15 = lane & 15, quad = lane >> 4;
  int oo0 = blockIdx.y * 64 + w * 16;
  int n0 = blockIdx.x * 64;

  f32x4 acc[4];
#pragma unroll
  for (int j = 0; j < 4; j++) acc[j] = (f32x4){0.f, 0.f, 0.f, 0.f};

  for (int kk = 0; kk < 16; kk++) {
    int c0 = kk * 32;
    __syncthreads();
#pragma unroll
    for (int i = 0; i < 8; i++) {
      int cc = i * 4 + w;
      xsT[lane][cc] = (bf16_t)feats[((size_t)b * Cn + c0 + cc) * Nn + n0 + lane];
    }
    __syncthreads();
    bf16x8 a = *(const bf16x8*)(bcwF + (size_t)(oo0 + l15) * 1024 + c0 + quad * 8);
#pragma unroll
    for (int j = 0; j < 4; j++) {
      bf16x8 bx = *(const bf16x8*)(&xsT[j * 16 + l15][quad * 8]);
      acc[j] = MFMA16(a, bx, acc[j]);
    }
  }
  for (int kk = 0; kk < 16; kk++) {
    int c0 = kk * 32;
    bf16x8 a = *(const bf16x8*)(bcwF + (size_t)(oo0 + l15) * 1024 + 512 + c0 + quad * 8);
#pragma unroll
    for (int j = 0; j < 4; j++) {
      bf16x8 bw = *(const bf16x8*)(wyBF + ((size_t)b * Nn + n0 + j * 16 + l15) * 512 + c0 + quad * 8);
      acc[j] = MFMA16(a, bw, acc[j]);
    }
  }

  if (mode == 0) {
#pragma unroll
    for (int r = 0; r < 4; r++) {
      int row = oo0 + quad * 4 + r;
      float bv = biasF[row];
      float s = 0.f, q = 0.f;
#pragma unroll
      for (int j = 0; j < 4; j++) {
        float v = acc[j][r] + bv;
        s += v; q += v * v;
      }
      s += __shfl_xor(s, 1); q += __shfl_xor(q, 1);
      s += __shfl_xor(s, 2); q += __shfl_xor(q, 2);
      s += __shfl_xor(s, 4); q += __shfl_xor(q, 4);
      s += __shfl_xor(s, 8); q += __shfl_xor(q, 8);
      if (l15 == 0) {
        atomicAdd(&stats[row], (double)s);
        atomicAdd(&stats[512 + row], (double)q);
      }
    }
  } else {
#pragma unroll
    for (int r = 0; r < 4; r++) {
      int row = oo0 + quad * 4 + r;
      float bv = biasF[row];
      float sc = sO[row], tc = tO[row];
#pragma unroll
      for (int j = 0; j < 4; j++)
        out[((size_t)b * 512 + row) * Nn + n0 + j * 16 + l15] =
            (acc[j][r] + bv) * sc + tc;
    }
  }
}

extern "C" void kernel_launch(void* const* d_in, const int* in_sizes, int n_in,
                              void* d_out, int out_size, void* d_ws, size_t ws_size,
                              hipStream_t stream) {
  const float* feats = (const float*)d_in[0];

  char* ws = (char*)d_ws;
  bf16_t* WPAR = (bf16_t*)(ws + OFF_WPAR);
  float* biasF = (float*)(ws + OFF_BIASF);
  float* sW = (float*)(ws + OFF_SW);
  float* tW = (float*)(ws + OFF_TW2);
  float* sO = (float*)(ws + OFF_SO);
  float* tO = (float*)(ws + OFF_TO);
  double* statsWy = (double*)(ws + OFF_STATW);
  double* statsO = (double*)(ws + OFF_STATO);
  bf16_t* wyBF = (bf16_t*)(ws + OFF_WY);
  bf16_t* arena = (bf16_t*)(ws + OFF_ARENA);
  bf16_t* bcwF = (bf16_t*)(ws + OFF_ARENA);  // overlay: arena dead before k_fold

  static const unsigned par_off[14] = {
      (unsigned)P_TW, (unsigned)P_TB, (unsigned)P_PW, (unsigned)P_PB,
      (unsigned)P_GW, (unsigned)P_GB, (unsigned)P_WW, (unsigned)P_WB,
      (unsigned)P_WG, (unsigned)P_WBE, (unsigned)P_BCW, (unsigned)P_BCB,
      (unsigned)P_BCG, (unsigned)P_BCBE};
  WArgs wa;
  for (int i = 0; i < 14; i++) {
    wa.src[i] = (const float*)d_in[i + 1];
    wa.n[i] = (unsigned)in_sizes[i + 1];
    wa.off[i] = par_off[i];
  }

  hipMemsetAsync(ws + OFF_STATW, 0, 16384, stream);  // statsWy + statsO

  k_wconv<<<dim3(256, 14), 256, 0, stream>>>(wa, WPAR);
  for (int base = 0; base < 32; base += 16) {
    k_proj_qk<<<dim3(36, 4, 32), 256, 0, stream>>>(feats, WPAR, arena, base);
    k_proj_v<<<dim3(36, 4, 16), 256, 0, stream>>>(feats, WPAR, arena, base);
    k_attn_wy<<<dim3(36, 16), 256, 0, stream>>>(arena, WPAR, wyBF, base);
  }
  k_wy_stats<<<dim3(36, 8), 256, 0, stream>>>(wyBF, statsWy);
  k_bn_st<<<1, 512, 0, stream>>>(statsWy, WPAR + P_WG, WPAR + P_WBE, sW, tW, 1.0 / 18432.0);
  k_fold<<<512, 256, 0, stream>>>(WPAR, sW, tW, bcwF, biasF);
  k_final<<<dim3(36, 8, 8), 256, 0, stream>>>(feats, wyBF, bcwF, biasF, sO, tO, statsO,
                                              (float*)d_out, 0);
  k_bn_st<<<1, 512, 0, stream>>>(statsO, WPAR + P_BCG, WPAR + P_BCBE, sO, tO, 1.0 / 18432.0);
  k_final<<<dim3(36, 8, 8), 256, 0, stream>>>(feats, wyBF, bcwF, biasF, sO, tO, statsO,
                                              (float*)d_out, 1);
}

// Round 8
// 2167.204 us; speedup vs baseline: 1.1012x; 1.1012x over previous
//
#include <hip/hip_runtime.h>
#include <hip/hip_bf16.h>

#define EPS 1e-5f
#define Bn 8
#define Cn 512
#define Nn 2304
#define C1n 256
#define C2n 256
#define CGn 128

typedef __bf16 bf16_t;
typedef __bf16 bf16x8 __attribute__((ext_vector_type(8)));
typedef float f32x4 __attribute__((ext_vector_type(4)));

#define MFMA16(a, b, c) __builtin_amdgcn_mfma_f32_16x16x32_bf16(a, b, c, 0, 0, 0)

// ---------- WPAR element offsets (bf16 weight arena) ----------
static constexpr size_t P_TW = 0;            // (4,256,512)
static constexpr size_t P_TB = 524288;
static constexpr size_t P_PW = 525312;
static constexpr size_t P_PB = 1049600;
static constexpr size_t P_GW = 1050624;
static constexpr size_t P_GB = 1574912;
static constexpr size_t P_WW = 1575936;      // (4,128,256)
static constexpr size_t P_WB = 1707008;
static constexpr size_t P_WG = 1707520;
static constexpr size_t P_WBE = 1708032;
static constexpr size_t P_BCW = 1708544;     // (512,1024)
static constexpr size_t P_BCB = 2232832;
static constexpr size_t P_BCG = 2233344;
static constexpr size_t P_BCBE = 2233856;

// ---------- workspace layout (bytes); peak 80.0 MB (proven safe: 98.9 MB ran) ----------
static constexpr size_t OFF_WPAR  = 0;          // 4,468,736
static constexpr size_t OFF_BIASF = 4468736;
static constexpr size_t OFF_SW    = 4470784;
static constexpr size_t OFF_TW2   = 4472832;
static constexpr size_t OFF_SO    = 4474880;
static constexpr size_t OFF_TO    = 4476928;
static constexpr size_t OFF_STATW = 4478976;    // f64[1024] (memset w/ STATO)
static constexpr size_t OFF_STATO = 4487168;    // f64[1024]
static constexpr size_t OFF_WY    = 4495360;    // bf16 (B,N,512) 18,874,368
static constexpr size_t OFF_ARENA = 23369728;   // 16 slots x (Q+K+V); bcwF overlay
static constexpr size_t QS  = 589824;           // elems: 2304*256
static constexpr size_t SL3 = 3 * QS;           // elems per slot (Q,K,V)
// end = 23,369,728 + 16*3*1,179,648 = 79,992,832

// ---------- K0: convert 14 f32 weight inputs -> bf16 WPAR ----------
struct WArgs {
  const float* src[14];
  unsigned n[14];
  unsigned off[14];
};

__global__ __launch_bounds__(256) void k_wconv(WArgs a, bf16_t* __restrict__ par) {
  int which = blockIdx.y;
  const float* s = a.src[which];
  unsigned n = a.n[which];
  bf16_t* dst = par + a.off[which];
  size_t stride = (size_t)gridDim.x * blockDim.x;
  for (size_t i = (size_t)blockIdx.x * blockDim.x + threadIdx.x; i < n; i += stride)
    dst[i] = (bf16_t)s[i];
}

// ---------- K1a: theta/phi projection -> Q or K slot (N,256) ----------
__global__ __launch_bounds__(256) void k_proj_qk(
    const float* __restrict__ feats, const bf16_t* __restrict__ par,
    bf16_t* __restrict__ arena, int gb_base) {
  __shared__ alignas(16) bf16_t xsT[64][40];
  int z = blockIdx.z, s = z >> 1, p = z & 1;
  int gb = gb_base + s, g = gb >> 3, b = gb & 7;
  const bf16_t* W = par + (p == 0 ? P_TW : P_PW) + (size_t)g * C1n * Cn;
  const bf16_t* bias = par + (p == 0 ? P_TB : P_PB) + g * C1n;
  bf16_t* out = arena + (size_t)s * SL3 + (size_t)p * QS;

  int tid = threadIdx.x, w = tid >> 6, lane = tid & 63;
  int l15 = lane & 15, quad = lane >> 4;
  int m0 = blockIdx.x * 64;
  int o0 = blockIdx.y * 64;

  f32x4 acc[4];
#pragma unroll
  for (int j = 0; j < 4; j++) acc[j] = (f32x4){0.f, 0.f, 0.f, 0.f};

  for (int kk = 0; kk < 16; kk++) {
    int c0 = kk * 32;
    __syncthreads();
#pragma unroll
    for (int i = 0; i < 8; i++) {
      int cc = i * 4 + w;
      xsT[lane][cc] = (bf16_t)feats[((size_t)b * Cn + c0 + cc) * Nn + m0 + lane];
    }
    __syncthreads();
    bf16x8 a = *(const bf16x8*)(&xsT[w * 16 + l15][quad * 8]);
#pragma unroll
    for (int j = 0; j < 4; j++) {
      bf16x8 bw = *(const bf16x8*)(W + (size_t)(o0 + j * 16 + l15) * Cn + c0 + quad * 8);
      acc[j] = MFMA16(a, bw, acc[j]);
    }
  }
#pragma unroll
  for (int j = 0; j < 4; j++) {
    int col = o0 + j * 16 + l15;
    float bv = (float)bias[col];
#pragma unroll
    for (int r = 0; r < 4; r++)
      out[(size_t)(m0 + w * 16 + quad * 4 + r) * C1n + col] = (bf16_t)(acc[j][r] + bv);
  }
}

// ---------- K1b: g projection -> V slot (256,N) ----------
__global__ __launch_bounds__(256) void k_proj_v(
    const float* __restrict__ feats, const bf16_t* __restrict__ par,
    bf16_t* __restrict__ arena, int gb_base) {
  __shared__ alignas(16) bf16_t xsT[64][40];
  int s = blockIdx.z, gb = gb_base + s, g = gb >> 3, b = gb & 7;
  const bf16_t* W = par + P_GW + (size_t)g * C2n * Cn;
  const bf16_t* bias = par + P_GB + g * C2n;
  bf16_t* out = arena + (size_t)s * SL3 + 2 * QS;

  int tid = threadIdx.x, w = tid >> 6, lane = tid & 63;
  int l15 = lane & 15, quad = lane >> 4;
  int n0 = blockIdx.x * 64;
  int c20 = blockIdx.y * 64 + w * 16;

  f32x4 acc[4];
#pragma unroll
  for (int j = 0; j < 4; j++) acc[j] = (f32x4){0.f, 0.f, 0.f, 0.f};

  for (int kk = 0; kk < 16; kk++) {
    int c0 = kk * 32;
    __syncthreads();
#pragma unroll
    for (int i = 0; i < 8; i++) {
      int cc = i * 4 + w;
      xsT[lane][cc] = (bf16_t)feats[((size_t)b * Cn + c0 + cc) * Nn + n0 + lane];
    }
    __syncthreads();
    bf16x8 a = *(const bf16x8*)(W + (size_t)(c20 + l15) * Cn + c0 + quad * 8);
#pragma unroll
    for (int j = 0; j < 4; j++) {
      bf16x8 bx = *(const bf16x8*)(&xsT[j * 16 + l15][quad * 8]);
      acc[j] = MFMA16(a, bx, acc[j]);
    }
  }
#pragma unroll
  for (int r = 0; r < 4; r++) {
    int row = c20 + quad * 4 + r;
    float bv = (float)bias[row];
#pragma unroll
    for (int j = 0; j < 4; j++)
      out[(size_t)row * Nn + n0 + j * 16 + l15] = (bf16_t)(acc[j][r] + bv);
  }
}

// ---------- K2: attention (unnormalized exp, split-N over 4 waves) + fused W-conv ----------
// block = 16 Q-rows; wave w covers n in [w*576, w*576+576); additive O/l merge in LDS.
__global__ __launch_bounds__(256) void k_attn_wy(
    const bf16_t* __restrict__ arena, const bf16_t* __restrict__ par,
    bf16_t* __restrict__ wyBF, int gb_base) {
  __shared__ alignas(16) bf16_t pbuf[4][16 * 40];   //  5120 B
  __shared__ alignas(16) bf16_t obuf[4][16 * 264];  // 33792 B
  __shared__ float lbuf[4][16];                     //   256 B
  int s = blockIdx.y, gb = gb_base + s, g = gb >> 3, b = gb & 7;
  const bf16_t* Qp = arena + (size_t)s * SL3;
  const bf16_t* Kp = Qp + QS;
  const bf16_t* Vp = Qp + 2 * QS;

  int tid = threadIdx.x, w = tid >> 6, lane = tid & 63;
  int l15 = lane & 15, quad = lane >> 4;
  int m0 = blockIdx.x * 16;

  bf16x8 qf[8];
  const bf16_t* qrow = Qp + (size_t)(m0 + l15) * C1n + quad * 8;
#pragma unroll
  for (int kk = 0; kk < 8; kk++) qf[kk] = *(const bf16x8*)(qrow + kk * 32);

  f32x4 oacc[16];
#pragma unroll
  for (int ct = 0; ct < 16; ct++) oacc[ct] = (f32x4){0.f, 0.f, 0.f, 0.f};
  f32x4 lacc = (f32x4){0.f, 0.f, 0.f, 0.f};

  bf16x8 ones;
#pragma unroll
  for (int i = 0; i < 8; i++) ones[i] = (bf16_t)1.0f;

  const float SC = 0.0625f * 1.44269504088896f;  // exp(f/16) = exp2(f*SC)
  bf16_t* pw = pbuf[w];
  int nbeg = w * 576;

  for (int n0 = nbeg; n0 < nbeg + 576; n0 += 32) {
    f32x4 s0 = (f32x4){0.f, 0.f, 0.f, 0.f};
    f32x4 s1 = (f32x4){0.f, 0.f, 0.f, 0.f};
    const bf16_t* k0p = Kp + (size_t)(n0 + l15) * C1n + quad * 8;
    const bf16_t* k1p = k0p + 16 * C1n;
#pragma unroll
    for (int kk = 0; kk < 8; kk++) {
      s0 = MFMA16(qf[kk], *(const bf16x8*)(k0p + kk * 32), s0);
      s1 = MFMA16(qf[kk], *(const bf16x8*)(k1p + kk * 32), s1);
    }
#pragma unroll
    for (int r = 0; r < 4; r++) {
      s0[r] = exp2f(s0[r] * SC);
      s1[r] = exp2f(s1[r] * SC);
      pw[(quad * 4 + r) * 40 + l15] = (bf16_t)s0[r];
      pw[(quad * 4 + r) * 40 + 16 + l15] = (bf16_t)s1[r];
    }
    bf16x8 pa = *(const bf16x8*)(pw + l15 * 40 + quad * 8);
    lacc = MFMA16(pa, ones, lacc);
    const bf16_t* vbase = Vp + (size_t)l15 * Nn + n0 + quad * 8;
#pragma unroll
    for (int ct = 0; ct < 16; ct++) {
      bf16x8 vb = *(const bf16x8*)(vbase + (size_t)ct * 16 * Nn);
      oacc[ct] = MFMA16(pa, vb, oacc[ct]);
    }
  }

  // store partials (additive merge: no max/rescale needed)
  if (l15 == 0) {
#pragma unroll
    for (int r = 0; r < 4; r++) lbuf[w][quad * 4 + r] = lacc[r];
  }
#pragma unroll
  for (int ct = 0; ct < 16; ct++)
#pragma unroll
    for (int r = 0; r < 4; r++)
      obuf[w][(quad * 4 + r) * 264 + ct * 16 + l15] = (bf16_t)oacc[ct][r];
  __syncthreads();

  float inv[4];
#pragma unroll
  for (int r = 0; r < 4; r++) {
    int row = quad * 4 + r;
    inv[r] = 1.f / (lbuf[0][row] + lbuf[1][row] + lbuf[2][row] + lbuf[3][row]);
  }
  // merge this wave's ct-quarter into obuf[0] (each idx owned by exactly one thread)
#pragma unroll
  for (int cc = 0; cc < 4; cc++) {
    int ct = w * 4 + cc;
#pragma unroll
    for (int r = 0; r < 4; r++) {
      int idx = (quad * 4 + r) * 264 + ct * 16 + l15;
      float v = (float)obuf[0][idx] + (float)obuf[1][idx] +
                (float)obuf[2][idx] + (float)obuf[3][idx];
      obuf[0][idx] = (bf16_t)(v * inv[r]);
    }
  }
  __syncthreads();

  // fused W-conv: wave w computes o-tiles j = 2w, 2w+1 for the block's 16 rows
  const bf16_t* Wg = par + P_WW + (size_t)g * CGn * C2n;
  const bf16_t* wbias = par + P_WB + g * CGn;
  const bf16_t* yb = obuf[0];
  f32x4 wyacc[2];
  wyacc[0] = (f32x4){0.f, 0.f, 0.f, 0.f};
  wyacc[1] = (f32x4){0.f, 0.f, 0.f, 0.f};
#pragma unroll
  for (int kk = 0; kk < 8; kk++) {
    bf16x8 ya = *(const bf16x8*)(yb + l15 * 264 + kk * 32 + quad * 8);
#pragma unroll
    for (int jj = 0; jj < 2; jj++) {
      int j = w * 2 + jj;
      bf16x8 wv = *(const bf16x8*)(Wg + (size_t)(j * 16 + l15) * C2n + kk * 32 + quad * 8);
      wyacc[jj] = MFMA16(ya, wv, wyacc[jj]);
    }
  }
#pragma unroll
  for (int jj = 0; jj < 2; jj++) {
    int o = (w * 2 + jj) * 16 + l15;
    float bv = (float)wbias[o];
#pragma unroll
    for (int r = 0; r < 4; r++)
      wyBF[((size_t)b * Nn + m0 + quad * 4 + r) * 512 + g * 128 + o] =
          (bf16_t)(wyacc[jj][r] + bv);
  }
}

// ---------- wy BN stats (channel-last), f64 atomics ----------
__global__ __launch_bounds__(256) void k_wy_stats(const bf16_t* __restrict__ wyBF,
                                                  double* __restrict__ stats) {
  int b = blockIdx.y;
  int m0 = blockIdx.x * 64;
  int tid = threadIdx.x;
  double s0 = 0., q0 = 0., s1 = 0., q1 = 0.;
  const bf16_t* base = wyBF + ((size_t)b * Nn + m0) * 512;
  for (int i = 0; i < 64; i++) {
    double v0 = (double)(float)base[(size_t)i * 512 + tid];
    double v1 = (double)(float)base[(size_t)i * 512 + 256 + tid];
    s0 += v0; q0 += v0 * v0; s1 += v1; q1 += v1 * v1;
  }
  atomicAdd(&stats[tid], s0);
  atomicAdd(&stats[512 + tid], q0);
  atomicAdd(&stats[256 + tid], s1);
  atomicAdd(&stats[768 + tid], q1);
}

// ---------- BN scale/shift ----------
__global__ void k_bn_st(const double* __restrict__ stats, const bf16_t* __restrict__ gamma,
                        const bf16_t* __restrict__ beta, float* __restrict__ sArr,
                        float* __restrict__ tArr, double inv_count) {
  int ch = threadIdx.x;  // 512
  double mean = stats[ch] * inv_count;
  double var = stats[512 + ch] * inv_count - mean * mean;
  double s = (double)(float)gamma[ch] / sqrt(var + (double)EPS);
  sArr[ch] = (float)s;
  tArr[ch] = (float)((double)(float)beta[ch] - mean * s);
}

// ---------- fold wy-BN into bottleneck weights ----------
__global__ __launch_bounds__(256) void k_fold(
    const bf16_t* __restrict__ par, const float* __restrict__ sW,
    const float* __restrict__ tW, bf16_t* __restrict__ bcwF, float* __restrict__ biasF) {
  int oo = blockIdx.x;
  int tid = threadIdx.x;
  const bf16_t* row = par + P_BCW + (size_t)oo * 1024;
  bf16_t* orow = bcwF + (size_t)oo * 1024;
  float part = 0.f;
  for (int c = tid; c < 512; c += 256) orow[c] = row[c];
  for (int c = 512 + tid; c < 1024; c += 256) {
    float wv = (float)row[c];
    orow[c] = (bf16_t)(wv * sW[c - 512]);
    part += wv * tW[c - 512];
  }
  __shared__ float red[256];
  red[tid] = part;
  __syncthreads();
  for (int s = 128; s > 0; s >>= 1) {
    if (tid < s) red[tid] += red[tid + s];
    __syncthreads();
  }
  if (tid == 0) biasF[oo] = (float)par[P_BCB + oo] + red[0];
}

// ---------- final GEMM: mode 0 -> f64 atomic stats; mode 1 -> normalized f32 out ----------
__global__ __launch_bounds__(256) void k_final(
    const float* __restrict__ feats, const bf16_t* __restrict__ wyBF,
    const bf16_t* __restrict__ bcwF, const float* __restrict__ biasF,
    const float* __restrict__ sO, const float* __restrict__ tO,
    double* __restrict__ stats, float* __restrict__ out, int mode) {
  __shared__ alignas(16) bf16_t xsT[64][40];
  int b = blockIdx.z;
  int tid = threadIdx.x, w = tid >> 6, lane = tid & 63;
  int l15 = lane & 15, quad = lane >> 4;
  int oo0 = blockIdx.y * 64 + w * 16;
  int n0 = blockIdx.x * 64;

  f32x4 acc[4];
#pragma unroll
  for (int j = 0; j < 4; j++) acc[j] = (f32x4){0.f, 0.f, 0.f, 0.f};

  for (int kk = 0; kk < 16; kk++) {
    int c0 = kk * 32;
    __syncthreads();
#pragma unroll
    for (int i = 0; i < 8; i++) {
      int cc = i * 4 + w;
      xsT[lane][cc] = (bf16_t)feats[((size_t)b * Cn + c0 + cc) * Nn + n0 + lane];
    }
    __syncthreads();
    bf16x8 a = *(const bf16x8*)(bcwF + (size_t)(oo0 + l15) * 1024 + c0 + quad * 8);
#pragma unroll
    for (int j = 0; j < 4; j++) {
      bf16x8 bx = *(const bf16x8*)(&xsT[j * 16 + l15][quad * 8]);
      acc[j] = MFMA16(a, bx, acc[j]);
    }
  }
  for (int kk = 0; kk < 16; kk++) {
    int c0 = kk * 32;
    bf16x8 a = *(const bf16x8*)(bcwF + (size_t)(oo0 + l15) * 1024 + 512 + c0 + quad * 8);
#pragma unroll
    for (int j = 0; j < 4; j++) {
      bf16x8 bw = *(const bf16x8*)(wyBF + ((size_t)b * Nn + n0 + j * 16 + l15) * 512 + c0 + quad * 8);
      acc[j] = MFMA16(a, bw, acc[j]);
    }
  }

  if (mode == 0) {
#pragma unroll
    for (int r = 0; r < 4; r++) {
      int row = oo0 + quad * 4 + r;
      float bv = biasF[row];
      float s = 0.f, q = 0.f;
#pragma unroll
      for (int j = 0; j < 4; j++) {
        float v = acc[j][r] + bv;
        s += v; q += v * v;
      }
      s += __shfl_xor(s, 1); q += __shfl_xor(q, 1);
      s += __shfl_xor(s, 2); q += __shfl_xor(q, 2);
      s += __shfl_xor(s, 4); q += __shfl_xor(q, 4);
      s += __shfl_xor(s, 8); q += __shfl_xor(q, 8);
      if (l15 == 0) {
        atomicAdd(&stats[row], (double)s);
        atomicAdd(&stats[512 + row], (double)q);
      }
    }
  } else {
#pragma unroll
    for (int r = 0; r < 4; r++) {
      int row = oo0 + quad * 4 + r;
      float bv = biasF[row];
      float sc = sO[row], tc = tO[row];
#pragma unroll
      for (int j = 0; j < 4; j++)
        out[((size_t)b * 512 + row) * Nn + n0 + j * 16 + l15] =
            (acc[j][r] + bv) * sc + tc;
    }
  }
}

extern "C" void kernel_launch(void* const* d_in, const int* in_sizes, int n_in,
                              void* d_out, int out_size, void* d_ws, size_t ws_size,
                              hipStream_t stream) {
  const float* feats = (const float*)d_in[0];

  char* ws = (char*)d_ws;
  bf16_t* WPAR = (bf16_t*)(ws + OFF_WPAR);
  float* biasF = (float*)(ws + OFF_BIASF);
  float* sW = (float*)(ws + OFF_SW);
  float* tW = (float*)(ws + OFF_TW2);
  float* sO = (float*)(ws + OFF_SO);
  float* tO = (float*)(ws + OFF_TO);
  double* statsWy = (double*)(ws + OFF_STATW);
  double* statsO = (double*)(ws + OFF_STATO);
  bf16_t* wyBF = (bf16_t*)(ws + OFF_WY);
  bf16_t* arena = (bf16_t*)(ws + OFF_ARENA);
  bf16_t* bcwF = (bf16_t*)(ws + OFF_ARENA);  // overlay: arena dead before k_fold

  static const unsigned par_off[14] = {
      (unsigned)P_TW, (unsigned)P_TB, (unsigned)P_PW, (unsigned)P_PB,
      (unsigned)P_GW, (unsigned)P_GB, (unsigned)P_WW, (unsigned)P_WB,
      (unsigned)P_WG, (unsigned)P_WBE, (unsigned)P_BCW, (unsigned)P_BCB,
      (unsigned)P_BCG, (unsigned)P_BCBE};
  WArgs wa;
  for (int i = 0; i < 14; i++) {
    wa.src[i] = (const float*)d_in[i + 1];
    wa.n[i] = (unsigned)in_sizes[i + 1];
    wa.off[i] = par_off[i];
  }

  hipMemsetAsync(ws + OFF_STATW, 0, 16384, stream);  // statsWy + statsO

  k_wconv<<<dim3(256, 14), 256, 0, stream>>>(wa, WPAR);
  for (int base = 0; base < 32; base += 16) {
    k_proj_qk<<<dim3(36, 4, 32), 256, 0, stream>>>(feats, WPAR, arena, base);
    k_proj_v<<<dim3(36, 4, 16), 256, 0, stream>>>(feats, WPAR, arena, base);
    k_attn_wy<<<dim3(144, 16), 256, 0, stream>>>(arena, WPAR, wyBF, base);
  }
  k_wy_stats<<<dim3(36, 8), 256, 0, stream>>>(wyBF, statsWy);
  k_bn_st<<<1, 512, 0, stream>>>(statsWy, WPAR + P_WG, WPAR + P_WBE, sW, tW, 1.0 / 18432.0);
  k_fold<<<512, 256, 0, stream>>>(WPAR, sW, tW, bcwF, biasF);
  k_final<<<dim3(36, 8, 8), 256, 0, stream>>>(feats, wyBF, bcwF, biasF, sO, tO, statsO,
                                              (float*)d_out, 0);
  k_bn_st<<<1, 512, 0, stream>>>(statsO, WPAR + P_BCG, WPAR + P_BCBE, sO, tO, 1.0 / 18432.0);
  k_final<<<dim3(36, 8, 8), 256, 0, stream>>>(feats, wyBF, bcwF, biasF, sO, tO, statsO,
                                              (float*)d_out, 1);
}

// Round 9
// 1416.676 us; speedup vs baseline: 1.6846x; 1.5298x over previous
//
#include <hip/hip_runtime.h>
#include <hip/hip_bf16.h>

#define EPS 1e-5f
#define Bn 8
#define Cn 512
#define Nn 2304
#define C1n 256
#define C2n 256
#define CGn 128

typedef __bf16 bf16_t;
typedef __bf16 bf16x8 __attribute__((ext_vector_type(8)));
typedef float f32x4 __attribute__((ext_vector_type(4)));

#define MFMA16(a, b, c) __builtin_amdgcn_mfma_f32_16x16x32_bf16(a, b, c, 0, 0, 0)

// ---------- WPAR element offsets (bf16 weight arena) ----------
static constexpr size_t P_TW = 0;            // (4,256,512)
static constexpr size_t P_TB = 524288;
static constexpr size_t P_PW = 525312;
static constexpr size_t P_PB = 1049600;
static constexpr size_t P_GW = 1050624;
static constexpr size_t P_GB = 1574912;
static constexpr size_t P_WW = 1575936;      // (4,128,256)
static constexpr size_t P_WB = 1707008;
static constexpr size_t P_WG = 1707520;
static constexpr size_t P_WBE = 1708032;
static constexpr size_t P_BCW = 1708544;     // (512,1024)
static constexpr size_t P_BCB = 2232832;
static constexpr size_t P_BCG = 2233344;
static constexpr size_t P_BCBE = 2233856;

// ---------- workspace layout (bytes); peak 80.0 MB (proven safe: 98.9 MB ran) ----------
static constexpr size_t OFF_WPAR  = 0;          // 4,468,736
static constexpr size_t OFF_BIASF = 4468736;
static constexpr size_t OFF_SW    = 4470784;
static constexpr size_t OFF_TW2   = 4472832;
static constexpr size_t OFF_SO    = 4474880;
static constexpr size_t OFF_TO    = 4476928;
static constexpr size_t OFF_STATW = 4478976;    // f64[1024] (memset w/ STATO)
static constexpr size_t OFF_STATO = 4487168;    // f64[1024]
static constexpr size_t OFF_WY    = 4495360;    // bf16 (B,N,512) 18,874,368
static constexpr size_t OFF_ARENA = 23369728;   // 16 slots x (Q+K+V); bcwF overlay
static constexpr size_t QS  = 589824;           // elems: 2304*256
static constexpr size_t SL3 = 3 * QS;           // elems per slot (Q,K,V)
// end = 23,369,728 + 16*3*1,179,648 = 79,992,832

// ---------- K0: convert 14 f32 weight inputs -> bf16 WPAR ----------
struct WArgs {
  const float* src[14];
  unsigned n[14];
  unsigned off[14];
};

__global__ __launch_bounds__(256) void k_wconv(WArgs a, bf16_t* __restrict__ par) {
  int which = blockIdx.y;
  const float* s = a.src[which];
  unsigned n = a.n[which];
  bf16_t* dst = par + a.off[which];
  size_t stride = (size_t)gridDim.x * blockDim.x;
  for (size_t i = (size_t)blockIdx.x * blockDim.x + threadIdx.x; i < n; i += stride)
    dst[i] = (bf16_t)s[i];
}

// ---------- K1a: theta/phi projection -> Q or K slot (N,256) ----------
__global__ __launch_bounds__(256) void k_proj_qk(
    const float* __restrict__ feats, const bf16_t* __restrict__ par,
    bf16_t* __restrict__ arena, int gb_base) {
  __shared__ alignas(16) bf16_t xsT[64][40];
  int z = blockIdx.z, s = z >> 1, p = z & 1;
  int gb = gb_base + s, g = gb >> 3, b = gb & 7;
  const bf16_t* W = par + (p == 0 ? P_TW : P_PW) + (size_t)g * C1n * Cn;
  const bf16_t* bias = par + (p == 0 ? P_TB : P_PB) + g * C1n;
  bf16_t* out = arena + (size_t)s * SL3 + (size_t)p * QS;

  int tid = threadIdx.x, w = tid >> 6, lane = tid & 63;
  int l15 = lane & 15, quad = lane >> 4;
  int m0 = blockIdx.x * 64;
  int o0 = blockIdx.y * 64;

  f32x4 acc[4];
#pragma unroll
  for (int j = 0; j < 4; j++) acc[j] = (f32x4){0.f, 0.f, 0.f, 0.f};

  for (int kk = 0; kk < 16; kk++) {
    int c0 = kk * 32;
    __syncthreads();
#pragma unroll
    for (int i = 0; i < 8; i++) {
      int cc = i * 4 + w;
      xsT[lane][cc] = (bf16_t)feats[((size_t)b * Cn + c0 + cc) * Nn + m0 + lane];
    }
    __syncthreads();
    bf16x8 a = *(const bf16x8*)(&xsT[w * 16 + l15][quad * 8]);
#pragma unroll
    for (int j = 0; j < 4; j++) {
      bf16x8 bw = *(const bf16x8*)(W + (size_t)(o0 + j * 16 + l15) * Cn + c0 + quad * 8);
      acc[j] = MFMA16(a, bw, acc[j]);
    }
  }
#pragma unroll
  for (int j = 0; j < 4; j++) {
    int col = o0 + j * 16 + l15;
    float bv = (float)bias[col];
#pragma unroll
    for (int r = 0; r < 4; r++)
      out[(size_t)(m0 + w * 16 + quad * 4 + r) * C1n + col] = (bf16_t)(acc[j][r] + bv);
  }
}

// ---------- K1b: g projection -> V slot (256,N) ----------
__global__ __launch_bounds__(256) void k_proj_v(
    const float* __restrict__ feats, const bf16_t* __restrict__ par,
    bf16_t* __restrict__ arena, int gb_base) {
  __shared__ alignas(16) bf16_t xsT[64][40];
  int s = blockIdx.z, gb = gb_base + s, g = gb >> 3, b = gb & 7;
  const bf16_t* W = par + P_GW + (size_t)g * C2n * Cn;
  const bf16_t* bias = par + P_GB + g * C2n;
  bf16_t* out = arena + (size_t)s * SL3 + 2 * QS;

  int tid = threadIdx.x, w = tid >> 6, lane = tid & 63;
  int l15 = lane & 15, quad = lane >> 4;
  int n0 = blockIdx.x * 64;
  int c20 = blockIdx.y * 64 + w * 16;

  f32x4 acc[4];
#pragma unroll
  for (int j = 0; j < 4; j++) acc[j] = (f32x4){0.f, 0.f, 0.f, 0.f};

  for (int kk = 0; kk < 16; kk++) {
    int c0 = kk * 32;
    __syncthreads();
#pragma unroll
    for (int i = 0; i < 8; i++) {
      int cc = i * 4 + w;
      xsT[lane][cc] = (bf16_t)feats[((size_t)b * Cn + c0 + cc) * Nn + n0 + lane];
    }
    __syncthreads();
    bf16x8 a = *(const bf16x8*)(W + (size_t)(c20 + l15) * Cn + c0 + quad * 8);
#pragma unroll
    for (int j = 0; j < 4; j++) {
      bf16x8 bx = *(const bf16x8*)(&xsT[j * 16 + l15][quad * 8]);
      acc[j] = MFMA16(a, bx, acc[j]);
    }
  }
#pragma unroll
  for (int r = 0; r < 4; r++) {
    int row = c20 + quad * 4 + r;
    float bv = (float)bias[row];
#pragma unroll
    for (int j = 0; j < 4; j++)
      out[(size_t)row * Nn + n0 + j * 16 + l15] = (bf16_t)(acc[j][r] + bv);
  }
}

// ---------- K2: GEMM-style attention (LDS-staged K/V tiles) + fused W-conv ----------
// block = 64 Q-rows (wave owns 16, full N loop -> no merge); 64-key tiles in LDS.
__global__ __launch_bounds__(256) void k_attn_wy(
    const bf16_t* __restrict__ arena, const bf16_t* __restrict__ par,
    bf16_t* __restrict__ wyBF, int gb_base) {
  __shared__ alignas(16) bf16_t kbuf[64 * 264];    // K tile (n x 256c); reused as ybuf
  __shared__ alignas(16) bf16_t vbuf[256 * 72];    // V tile (c2 x 64n)
  __shared__ alignas(16) bf16_t pbuf[4][16 * 72];  // per-wave P roundtrip
  int s = blockIdx.y, gb = gb_base + s, g = gb >> 3, b = gb & 7;
  const bf16_t* Qp = arena + (size_t)s * SL3;
  const bf16_t* Kp = Qp + QS;
  const bf16_t* Vp = Qp + 2 * QS;

  int tid = threadIdx.x, w = tid >> 6, lane = tid & 63;
  int l15 = lane & 15, quad = lane >> 4;
  int m0 = blockIdx.x * 64;
  int mw = m0 + w * 16;

  bf16x8 qf[8];
  const bf16_t* qrow = Qp + (size_t)(mw + l15) * C1n + quad * 8;
#pragma unroll
  for (int kk = 0; kk < 8; kk++) qf[kk] = *(const bf16x8*)(qrow + kk * 32);

  f32x4 oacc[16];
#pragma unroll
  for (int ct = 0; ct < 16; ct++) oacc[ct] = (f32x4){0.f, 0.f, 0.f, 0.f};
  f32x4 lacc = (f32x4){0.f, 0.f, 0.f, 0.f};

  bf16x8 ones;
#pragma unroll
  for (int i = 0; i < 8; i++) ones[i] = (bf16_t)1.0f;

  const float SC = 0.0625f * 1.44269504088896f;  // exp(f/16) = exp2(f*SC)
  bf16_t* pw = pbuf[w];

  for (int n0 = 0; n0 < Nn; n0 += 64) {
    __syncthreads();  // prior tile's LDS reads complete before overwrite
    // stage K tile: 64 rows x 512B (16B/thread x 8)
#pragma unroll
    for (int e = 0; e < 8; e++) {
      int idx = e * 256 + tid;
      int row = idx >> 5, cc = (idx & 31) * 8;
      *(bf16x8*)(kbuf + row * 264 + cc) =
          *(const bf16x8*)(Kp + (size_t)(n0 + row) * C1n + cc);
    }
    // stage V tile: 256 c2-rows x 128B
#pragma unroll
    for (int e = 0; e < 8; e++) {
      int idx = e * 256 + tid;
      int row = idx >> 3, cc = (idx & 7) * 8;
      *(bf16x8*)(vbuf + row * 72 + cc) =
          *(const bf16x8*)(Vp + (size_t)row * Nn + n0 + cc);
    }
    __syncthreads();

    // QK: S[16 rows x 64 keys]
    f32x4 sacc[4];
#pragma unroll
    for (int nt = 0; nt < 4; nt++) sacc[nt] = (f32x4){0.f, 0.f, 0.f, 0.f};
#pragma unroll
    for (int kk = 0; kk < 8; kk++) {
#pragma unroll
      for (int nt = 0; nt < 4; nt++) {
        bf16x8 kb = *(const bf16x8*)(kbuf + (nt * 16 + l15) * 264 + kk * 32 + quad * 8);
        sacc[nt] = MFMA16(qf[kk], kb, sacc[nt]);
      }
    }
    // P = exp, C-layout -> A-layout roundtrip (per-wave, DS in-order)
#pragma unroll
    for (int nt = 0; nt < 4; nt++)
#pragma unroll
      for (int r = 0; r < 4; r++)
        pw[(quad * 4 + r) * 72 + nt * 16 + l15] = (bf16_t)exp2f(sacc[nt][r] * SC);
    bf16x8 pa0 = *(const bf16x8*)(pw + l15 * 72 + quad * 8);
    bf16x8 pa1 = *(const bf16x8*)(pw + l15 * 72 + 32 + quad * 8);
    lacc = MFMA16(pa0, ones, lacc);
    lacc = MFMA16(pa1, ones, lacc);
    // PV from LDS V tile
#pragma unroll
    for (int ct = 0; ct < 16; ct++) {
      bf16x8 v0 = *(const bf16x8*)(vbuf + (ct * 16 + l15) * 72 + quad * 8);
      bf16x8 v1 = *(const bf16x8*)(vbuf + (ct * 16 + l15) * 72 + 32 + quad * 8);
      oacc[ct] = MFMA16(pa0, v0, oacc[ct]);
      oacc[ct] = MFMA16(pa1, v1, oacc[ct]);
    }
  }

  float inv[4];
#pragma unroll
  for (int r = 0; r < 4; r++) inv[r] = 1.f / lacc[r];

  __syncthreads();  // all waves done with kbuf before reuse as ybuf
  bf16_t* yb = kbuf + (size_t)w * 16 * 264;
#pragma unroll
  for (int ct = 0; ct < 16; ct++)
#pragma unroll
    for (int r = 0; r < 4; r++)
      yb[(quad * 4 + r) * 264 + ct * 16 + l15] = (bf16_t)(oacc[ct][r] * inv[r]);

  // fused W-conv: wy[16 x 128] = y[16 x 256] @ Wg^T
  const bf16_t* Wg = par + P_WW + (size_t)g * CGn * C2n;
  const bf16_t* wbias = par + P_WB + g * CGn;
  f32x4 wyacc[8];
#pragma unroll
  for (int j = 0; j < 8; j++) wyacc[j] = (f32x4){0.f, 0.f, 0.f, 0.f};
#pragma unroll
  for (int kk = 0; kk < 8; kk++) {
    bf16x8 ya = *(const bf16x8*)(yb + l15 * 264 + kk * 32 + quad * 8);
#pragma unroll
    for (int j = 0; j < 8; j++) {
      bf16x8 wv = *(const bf16x8*)(Wg + (size_t)(j * 16 + l15) * C2n + kk * 32 + quad * 8);
      wyacc[j] = MFMA16(ya, wv, wyacc[j]);
    }
  }
#pragma unroll
  for (int j = 0; j < 8; j++) {
    int o = j * 16 + l15;
    float bv = (float)wbias[o];
#pragma unroll
    for (int r = 0; r < 4; r++)
      wyBF[((size_t)b * Nn + mw + quad * 4 + r) * 512 + g * 128 + o] =
          (bf16_t)(wyacc[j][r] + bv);
  }
}

// ---------- wy BN stats (channel-last), f64 atomics ----------
__global__ __launch_bounds__(256) void k_wy_stats(const bf16_t* __restrict__ wyBF,
                                                  double* __restrict__ stats) {
  int b = blockIdx.y;
  int m0 = blockIdx.x * 64;
  int tid = threadIdx.x;
  double s0 = 0., q0 = 0., s1 = 0., q1 = 0.;
  const bf16_t* base = wyBF + ((size_t)b * Nn + m0) * 512;
  for (int i = 0; i < 64; i++) {
    double v0 = (double)(float)base[(size_t)i * 512 + tid];
    double v1 = (double)(float)base[(size_t)i * 512 + 256 + tid];
    s0 += v0; q0 += v0 * v0; s1 += v1; q1 += v1 * v1;
  }
  atomicAdd(&stats[tid], s0);
  atomicAdd(&stats[512 + tid], q0);
  atomicAdd(&stats[256 + tid], s1);
  atomicAdd(&stats[768 + tid], q1);
}

// ---------- BN scale/shift ----------
__global__ void k_bn_st(const double* __restrict__ stats, const bf16_t* __restrict__ gamma,
                        const bf16_t* __restrict__ beta, float* __restrict__ sArr,
                        float* __restrict__ tArr, double inv_count) {
  int ch = threadIdx.x;  // 512
  double mean = stats[ch] * inv_count;
  double var = stats[512 + ch] * inv_count - mean * mean;
  double s = (double)(float)gamma[ch] / sqrt(var + (double)EPS);
  sArr[ch] = (float)s;
  tArr[ch] = (float)((double)(float)beta[ch] - mean * s);
}

// ---------- fold wy-BN into bottleneck weights ----------
__global__ __launch_bounds__(256) void k_fold(
    const bf16_t* __restrict__ par, const float* __restrict__ sW,
    const float* __restrict__ tW, bf16_t* __restrict__ bcwF, float* __restrict__ biasF) {
  int oo = blockIdx.x;
  int tid = threadIdx.x;
  const bf16_t* row = par + P_BCW + (size_t)oo * 1024;
  bf16_t* orow = bcwF + (size_t)oo * 1024;
  float part = 0.f;
  for (int c = tid; c < 512; c += 256) orow[c] = row[c];
  for (int c = 512 + tid; c < 1024; c += 256) {
    float wv = (float)row[c];
    orow[c] = (bf16_t)(wv * sW[c - 512]);
    part += wv * tW[c - 512];
  }
  __shared__ float red[256];
  red[tid] = part;
  __syncthreads();
  for (int s = 128; s > 0; s >>= 1) {
    if (tid < s) red[tid] += red[tid + s];
    __syncthreads();
  }
  if (tid == 0) biasF[oo] = (float)par[P_BCB + oo] + red[0];
}

// ---------- final GEMM: mode 0 -> f64 atomic stats; mode 1 -> normalized f32 out ----------
__global__ __launch_bounds__(256) void k_final(
    const float* __restrict__ feats, const bf16_t* __restrict__ wyBF,
    const bf16_t* __restrict__ bcwF, const float* __restrict__ biasF,
    const float* __restrict__ sO, const float* __restrict__ tO,
    double* __restrict__ stats, float* __restrict__ out, int mode) {
  __shared__ alignas(16) bf16_t xsT[64][40];
  int b = blockIdx.z;
  int tid = threadIdx.x, w = tid >> 6, lane = tid & 63;
  int l15 = lane & 15, quad = lane >> 4;
  int oo0 = blockIdx.y * 64 + w * 16;
  int n0 = blockIdx.x * 64;

  f32x4 acc[4];
#pragma unroll
  for (int j = 0; j < 4; j++) acc[j] = (f32x4){0.f, 0.f, 0.f, 0.f};

  for (int kk = 0; kk < 16; kk++) {
    int c0 = kk * 32;
    __syncthreads();
#pragma unroll
    for (int i = 0; i < 8; i++) {
      int cc = i * 4 + w;
      xsT[lane][cc] = (bf16_t)feats[((size_t)b * Cn + c0 + cc) * Nn + n0 + lane];
    }
    __syncthreads();
    bf16x8 a = *(const bf16x8*)(bcwF + (size_t)(oo0 + l15) * 1024 + c0 + quad * 8);
#pragma unroll
    for (int j = 0; j < 4; j++) {
      bf16x8 bx = *(const bf16x8*)(&xsT[j * 16 + l15][quad * 8]);
      acc[j] = MFMA16(a, bx, acc[j]);
    }
  }
  for (int kk = 0; kk < 16; kk++) {
    int c0 = kk * 32;
    bf16x8 a = *(const bf16x8*)(bcwF + (size_t)(oo0 + l15) * 1024 + 512 + c0 + quad * 8);
#pragma unroll
    for (int j = 0; j < 4; j++) {
      bf16x8 bw = *(const bf16x8*)(wyBF + ((size_t)b * Nn + n0 + j * 16 + l15) * 512 + c0 + quad * 8);
      acc[j] = MFMA16(a, bw, acc[j]);
    }
  }

  if (mode == 0) {
#pragma unroll
    for (int r = 0; r < 4; r++) {
      int row = oo0 + quad * 4 + r;
      float bv = biasF[row];
      float s = 0.f, q = 0.f;
#pragma unroll
      for (int j = 0; j < 4; j++) {
        float v = acc[j][r] + bv;
        s += v; q += v * v;
      }
      s += __shfl_xor(s, 1); q += __shfl_xor(q, 1);
      s += __shfl_xor(s, 2); q += __shfl_xor(q, 2);
      s += __shfl_xor(s, 4); q += __shfl_xor(q, 4);
      s += __shfl_xor(s, 8); q += __shfl_xor(q, 8);
      if (l15 == 0) {
        atomicAdd(&stats[row], (double)s);
        atomicAdd(&stats[512 + row], (double)q);
      }
    }
  } else {
#pragma unroll
    for (int r = 0; r < 4; r++) {
      int row = oo0 + quad * 4 + r;
      float bv = biasF[row];
      float sc = sO[row], tc = tO[row];
#pragma unroll
      for (int j = 0; j < 4; j++)
        out[((size_t)b * 512 + row) * Nn + n0 + j * 16 + l15] =
            (acc[j][r] + bv) * sc + tc;
    }
  }
}

extern "C" void kernel_launch(void* const* d_in, const int* in_sizes, int n_in,
                              void* d_out, int out_size, void* d_ws, size_t ws_size,
                              hipStream_t stream) {
  const float* feats = (const float*)d_in[0];

  char* ws = (char*)d_ws;
  bf16_t* WPAR = (bf16_t*)(ws + OFF_WPAR);
  float* biasF = (float*)(ws + OFF_BIASF);
  float* sW = (float*)(ws + OFF_SW);
  float* tW = (float*)(ws + OFF_TW2);
  float* sO = (float*)(ws + OFF_SO);
  float* tO = (float*)(ws + OFF_TO);
  double* statsWy = (double*)(ws + OFF_STATW);
  double* statsO = (double*)(ws + OFF_STATO);
  bf16_t* wyBF = (bf16_t*)(ws + OFF_WY);
  bf16_t* arena = (bf16_t*)(ws + OFF_ARENA);
  bf16_t* bcwF = (bf16_t*)(ws + OFF_ARENA);  // overlay: arena dead before k_fold

  static const unsigned par_off[14] = {
      (unsigned)P_TW, (unsigned)P_TB, (unsigned)P_PW, (unsigned)P_PB,
      (unsigned)P_GW, (unsigned)P_GB, (unsigned)P_WW, (unsigned)P_WB,
      (unsigned)P_WG, (unsigned)P_WBE, (unsigned)P_BCW, (unsigned)P_BCB,
      (unsigned)P_BCG, (unsigned)P_BCBE};
  WArgs wa;
  for (int i = 0; i < 14; i++) {
    wa.src[i] = (const float*)d_in[i + 1];
    wa.n[i] = (unsigned)in_sizes[i + 1];
    wa.off[i] = par_off[i];
  }

  hipMemsetAsync(ws + OFF_STATW, 0, 16384, stream);  // statsWy + statsO

  k_wconv<<<dim3(256, 14), 256, 0, stream>>>(wa, WPAR);
  for (int base = 0; base < 32; base += 16) {
    k_proj_qk<<<dim3(36, 4, 32), 256, 0, stream>>>(feats, WPAR, arena, base);
    k_proj_v<<<dim3(36, 4, 16), 256, 0, stream>>>(feats, WPAR, arena, base);
    k_attn_wy<<<dim3(36, 16), 256, 0, stream>>>(arena, WPAR, wyBF, base);
  }
  k_wy_stats<<<dim3(36, 8), 256, 0, stream>>>(wyBF, statsWy);
  k_bn_st<<<1, 512, 0, stream>>>(statsWy, WPAR + P_WG, WPAR + P_WBE, sW, tW, 1.0 / 18432.0);
  k_fold<<<512, 256, 0, stream>>>(WPAR, sW, tW, bcwF, biasF);
  k_final<<<dim3(36, 8, 8), 256, 0, stream>>>(feats, wyBF, bcwF, biasF, sO, tO, statsO,
                                              (float*)d_out, 0);
  k_bn_st<<<1, 512, 0, stream>>>(statsO, WPAR + P_BCG, WPAR + P_BCBE, sO, tO, 1.0 / 18432.0);
  k_final<<<dim3(36, 8, 8), 256, 0, stream>>>(feats, wyBF, bcwF, biasF, sO, tO, statsO,
                                              (float*)d_out, 1);
}

// Round 10
// 1292.307 us; speedup vs baseline: 1.8468x; 1.0962x over previous
//
#include <hip/hip_runtime.h>
#include <hip/hip_bf16.h>

#define EPS 1e-5f
#define Bn 8
#define Cn 512
#define Nn 2304
#define C1n 256
#define C2n 256
#define CGn 128

typedef __bf16 bf16_t;
typedef __bf16 bf16x8 __attribute__((ext_vector_type(8)));
typedef float f32x4 __attribute__((ext_vector_type(4)));

#define MFMA16(a, b, c) __builtin_amdgcn_mfma_f32_16x16x32_bf16(a, b, c, 0, 0, 0)

// ---------- WPAR element offsets (bf16 weight arena) ----------
static constexpr size_t P_TW = 0;            // (4,256,512)
static constexpr size_t P_TB = 524288;
static constexpr size_t P_PW = 525312;
static constexpr size_t P_PB = 1049600;
static constexpr size_t P_GW = 1050624;
static constexpr size_t P_GB = 1574912;
static constexpr size_t P_WW = 1575936;      // (4,128,256)
static constexpr size_t P_WB = 1707008;
static constexpr size_t P_WG = 1707520;
static constexpr size_t P_WBE = 1708032;
static constexpr size_t P_BCW = 1708544;     // (512,1024)
static constexpr size_t P_BCB = 2232832;
static constexpr size_t P_BCG = 2233344;
static constexpr size_t P_BCBE = 2233856;

// ---------- workspace layout (bytes); end = 79,992,832 (proven safe in r7-r9) ----------
static constexpr size_t OFF_WPAR  = 0;          // 4,468,736
static constexpr size_t OFF_BIASF = 4468736;
static constexpr size_t OFF_SW    = 4470784;
static constexpr size_t OFF_TW2   = 4472832;
static constexpr size_t OFF_SO    = 4474880;
static constexpr size_t OFF_TO    = 4476928;
static constexpr size_t OFF_STATW = 4478976;    // f64[1024]
static constexpr size_t OFF_STATO = 4487168;    // f64[1024]
static constexpr size_t OFF_ARENA = 4495360;    // 32 slots x (K+V) = 75,497,472
static constexpr size_t QS  = 589824;           // elems: 2304*256
static constexpr size_t SL2 = 2 * QS;           // elems per slot (K,V)
// post-attn overlays inside the dead arena:
static constexpr size_t OVL_BCWF = OFF_ARENA;             // 1,048,576
static constexpr size_t OVL_WY   = OFF_ARENA + 2097152;   // 18,874,368

// ---------- K0: convert 14 f32 weight inputs -> bf16 WPAR ----------
struct WArgs {
  const float* src[14];
  unsigned n[14];
  unsigned off[14];
};

__global__ __launch_bounds__(256) void k_wconv(WArgs a, bf16_t* __restrict__ par) {
  int which = blockIdx.y;
  const float* s = a.src[which];
  unsigned n = a.n[which];
  bf16_t* dst = par + a.off[which];
  size_t stride = (size_t)gridDim.x * blockDim.x;
  for (size_t i = (size_t)blockIdx.x * blockDim.x + threadIdx.x; i < n; i += stride)
    dst[i] = (bf16_t)s[i];
}

// ---------- K1: K (phi) and V (g) projections for all 32 slots, one launch ----------
// z = slot*2 + p (p=0: K (N,256); p=1: V (256,N))
__global__ __launch_bounds__(256) void k_projKV(
    const float* __restrict__ feats, const bf16_t* __restrict__ par,
    bf16_t* __restrict__ arena) {
  __shared__ alignas(16) bf16_t xsT[64][40];
  int z = blockIdx.z, s = z >> 1, p = z & 1;
  int g = s >> 3, b = s & 7;
  int tid = threadIdx.x, w = tid >> 6, lane = tid & 63;
  int l15 = lane & 15, quad = lane >> 4;

  if (p == 0) {
    const bf16_t* W = par + P_PW + (size_t)g * C1n * Cn;
    const bf16_t* bias = par + P_PB + g * C1n;
    bf16_t* out = arena + (size_t)s * SL2;
    int m0 = blockIdx.x * 64;
    int o0 = blockIdx.y * 64;
    f32x4 acc[4];
#pragma unroll
    for (int j = 0; j < 4; j++) acc[j] = (f32x4){0.f, 0.f, 0.f, 0.f};
    for (int kk = 0; kk < 16; kk++) {
      int c0 = kk * 32;
      __syncthreads();
#pragma unroll
      for (int i = 0; i < 8; i++) {
        int cc = i * 4 + w;
        xsT[lane][cc] = (bf16_t)feats[((size_t)b * Cn + c0 + cc) * Nn + m0 + lane];
      }
      __syncthreads();
      bf16x8 a = *(const bf16x8*)(&xsT[w * 16 + l15][quad * 8]);
#pragma unroll
      for (int j = 0; j < 4; j++) {
        bf16x8 bw = *(const bf16x8*)(W + (size_t)(o0 + j * 16 + l15) * Cn + c0 + quad * 8);
        acc[j] = MFMA16(a, bw, acc[j]);
      }
    }
#pragma unroll
    for (int j = 0; j < 4; j++) {
      int col = o0 + j * 16 + l15;
      float bv = (float)bias[col];
#pragma unroll
      for (int r = 0; r < 4; r++)
        out[(size_t)(m0 + w * 16 + quad * 4 + r) * C1n + col] = (bf16_t)(acc[j][r] + bv);
    }
  } else {
    const bf16_t* W = par + P_GW + (size_t)g * C2n * Cn;
    const bf16_t* bias = par + P_GB + g * C2n;
    bf16_t* out = arena + (size_t)s * SL2 + QS;
    int n0 = blockIdx.x * 64;
    int c20 = blockIdx.y * 64 + w * 16;
    f32x4 acc[4];
#pragma unroll
    for (int j = 0; j < 4; j++) acc[j] = (f32x4){0.f, 0.f, 0.f, 0.f};
    for (int kk = 0; kk < 16; kk++) {
      int c0 = kk * 32;
      __syncthreads();
#pragma unroll
      for (int i = 0; i < 8; i++) {
        int cc = i * 4 + w;
        xsT[lane][cc] = (bf16_t)feats[((size_t)b * Cn + c0 + cc) * Nn + n0 + lane];
      }
      __syncthreads();
      bf16x8 a = *(const bf16x8*)(W + (size_t)(c20 + l15) * Cn + c0 + quad * 8);
#pragma unroll
      for (int j = 0; j < 4; j++) {
        bf16x8 bx = *(const bf16x8*)(&xsT[j * 16 + l15][quad * 8]);
        acc[j] = MFMA16(a, bx, acc[j]);
      }
    }
#pragma unroll
    for (int r = 0; r < 4; r++) {
      int row = c20 + quad * 4 + r;
      float bv = (float)bias[row];
#pragma unroll
      for (int j = 0; j < 4; j++)
        out[(size_t)row * Nn + n0 + j * 16 + l15] = (bf16_t)(acc[j][r] + bv);
    }
  }
}

// ---------- K2: attention, 128 rows/block, 32 rows/wave, on-the-fly Q ----------
// One launch: grid (18, 32). wy (bf16) written to d_out scratch.
__global__ __launch_bounds__(256, 2) void k_attn_wy(
    const float* __restrict__ feats, const bf16_t* __restrict__ arena,
    const bf16_t* __restrict__ par, bf16_t* __restrict__ wyOut) {
  // sh = kbuf[32*264] | vbuf[256*40] | pbuf[4*32*40]
  __shared__ alignas(16) bf16_t sh[8448 + 10240 + 5120];
  bf16_t* kbuf = sh;
  bf16_t* vbuf = sh + 8448;

  int gb = blockIdx.y, g = gb >> 3, b = gb & 7;
  const bf16_t* Kp = arena + (size_t)gb * SL2;
  const bf16_t* Vp = Kp + QS;

  int tid = threadIdx.x, w = tid >> 6, lane = tid & 63;
  int l15 = lane & 15, quad = lane >> 4;
  int m0 = blockIdx.x * 128;
  int mw0 = m0 + w * 32;
  bf16_t* pw = sh + 8448 + 10240 + w * 1280;  // per-wave 32x40

  // ---- phase Q: qf[rt*8+kc8] = Q A-frags for this wave's 32 rows ----
  bf16x8 qf[16];
  {
    bf16_t* xs = sh + w * 1280;  // per-wave 32x40 (inside kbuf region)
    const bf16_t* Wt = par + P_TW + (size_t)g * C1n * Cn;
    const bf16_t* tb = par + P_TB + g * C1n;
    f32x4 qacc[2][16];
#pragma unroll
    for (int rt = 0; rt < 2; rt++)
#pragma unroll
      for (int ot = 0; ot < 16; ot++) qacc[rt][ot] = (f32x4){0.f, 0.f, 0.f, 0.f};

    for (int kc = 0; kc < 16; kc++) {
      // stage own 32 rows x 32 c (wave-private, no barrier)
#pragma unroll
      for (int ps = 0; ps < 16; ps++) {
        int idx = ps * 64 + lane;
        int cc = idx >> 5, nn = idx & 31;
        xs[nn * 40 + cc] = (bf16_t)feats[((size_t)b * Cn + kc * 32 + cc) * Nn + mw0 + nn];
      }
#pragma unroll
      for (int rt = 0; rt < 2; rt++) {
        bf16x8 a = *(const bf16x8*)(xs + (rt * 16 + l15) * 40 + quad * 8);
#pragma unroll
        for (int ot = 0; ot < 16; ot++) {
          bf16x8 bw = *(const bf16x8*)(Wt + (size_t)(ot * 16 + l15) * Cn + kc * 32 + quad * 8);
          qacc[rt][ot] = MFMA16(a, bw, qacc[rt][ot]);
        }
      }
    }
    // C-layout -> A-frags via per-wave roundtrip (qt = pw, 16x40)
#pragma unroll
    for (int rt = 0; rt < 2; rt++)
#pragma unroll
      for (int kc8 = 0; kc8 < 8; kc8++) {
#pragma unroll
        for (int h = 0; h < 2; h++) {
          int ot = kc8 * 2 + h;
          float bv = (float)tb[ot * 16 + l15];
#pragma unroll
          for (int r = 0; r < 4; r++)
            pw[(quad * 4 + r) * 40 + h * 16 + l15] = (bf16_t)(qacc[rt][ot][r] + bv);
        }
        qf[rt * 8 + kc8] = *(const bf16x8*)(pw + l15 * 40 + quad * 8);
      }
  }

  // ---- main loop over 32-key tiles ----
  f32x4 oacc[2][16];
#pragma unroll
  for (int rt = 0; rt < 2; rt++)
#pragma unroll
    for (int ct = 0; ct < 16; ct++) oacc[rt][ct] = (f32x4){0.f, 0.f, 0.f, 0.f};
  f32x4 lacc[2];
  lacc[0] = (f32x4){0.f, 0.f, 0.f, 0.f};
  lacc[1] = (f32x4){0.f, 0.f, 0.f, 0.f};

  bf16x8 ones;
#pragma unroll
  for (int i = 0; i < 8; i++) ones[i] = (bf16_t)1.0f;
  const float SC = 0.0625f * 1.44269504088896f;  // exp(f/16) = exp2(f*SC)

  for (int n0 = 0; n0 < Nn; n0 += 32) {
    __syncthreads();
    // stage K tile 32x256 (4 b128/thread)
#pragma unroll
    for (int e = 0; e < 4; e++) {
      int cid = e * 256 + tid;
      int row = cid >> 5, c8 = (cid & 31) * 8;
      *(bf16x8*)(kbuf + row * 264 + c8) = *(const bf16x8*)(Kp + (size_t)(n0 + row) * C1n + c8);
    }
    // stage V tile 256x32 (4 b128/thread)
#pragma unroll
    for (int e = 0; e < 4; e++) {
      int cid = e * 256 + tid;
      int row = cid >> 2, k8 = (cid & 3) * 8;
      *(bf16x8*)(vbuf + row * 40 + k8) = *(const bf16x8*)(Vp + (size_t)row * Nn + n0 + k8);
    }
    __syncthreads();

    // QK: 2 rt x 2 nt, each B-read feeds 2 MFMA
    f32x4 sacc[2][2];
#pragma unroll
    for (int rt = 0; rt < 2; rt++)
#pragma unroll
      for (int nt = 0; nt < 2; nt++) sacc[rt][nt] = (f32x4){0.f, 0.f, 0.f, 0.f};
#pragma unroll
    for (int ks = 0; ks < 8; ks++) {
#pragma unroll
      for (int nt = 0; nt < 2; nt++) {
        bf16x8 kb = *(const bf16x8*)(kbuf + (nt * 16 + l15) * 264 + ks * 32 + quad * 8);
        sacc[0][nt] = MFMA16(qf[ks], kb, sacc[0][nt]);
        sacc[1][nt] = MFMA16(qf[8 + ks], kb, sacc[1][nt]);
      }
    }
    // exp -> P (bf16, per-wave roundtrip)
#pragma unroll
    for (int rt = 0; rt < 2; rt++)
#pragma unroll
      for (int nt = 0; nt < 2; nt++)
#pragma unroll
        for (int r = 0; r < 4; r++)
          pw[(rt * 16 + quad * 4 + r) * 40 + nt * 16 + l15] =
              (bf16_t)exp2f(sacc[rt][nt][r] * SC);
    bf16x8 pa0 = *(const bf16x8*)(pw + l15 * 40 + quad * 8);
    bf16x8 pa1 = *(const bf16x8*)(pw + (16 + l15) * 40 + quad * 8);
    lacc[0] = MFMA16(pa0, ones, lacc[0]);
    lacc[1] = MFMA16(pa1, ones, lacc[1]);
    // PV: each V-read feeds 2 MFMA
#pragma unroll
    for (int ct = 0; ct < 16; ct++) {
      bf16x8 vb = *(const bf16x8*)(vbuf + (ct * 16 + l15) * 40 + quad * 8);
      oacc[0][ct] = MFMA16(pa0, vb, oacc[0][ct]);
      oacc[1][ct] = MFMA16(pa1, vb, oacc[1][ct]);
    }
  }

  float inv[2][4];
#pragma unroll
  for (int rt = 0; rt < 2; rt++)
#pragma unroll
    for (int r = 0; r < 4; r++) inv[rt][r] = 1.f / lacc[rt][r];

  // ---- epilogue: y -> A-frags -> W-conv -> wy (d_out scratch) ----
  const bf16_t* Wg = par + P_WW + (size_t)g * CGn * C2n;
  const bf16_t* wbias = par + P_WB + g * CGn;
#pragma unroll
  for (int rt = 0; rt < 2; rt++) {
    bf16x8 yf[8];
#pragma unroll
    for (int kc8 = 0; kc8 < 8; kc8++) {
#pragma unroll
      for (int h = 0; h < 2; h++) {
        int ct = kc8 * 2 + h;
#pragma unroll
        for (int r = 0; r < 4; r++)
          pw[(quad * 4 + r) * 40 + h * 16 + l15] = (bf16_t)(oacc[rt][ct][r] * inv[rt][r]);
      }
      yf[kc8] = *(const bf16x8*)(pw + l15 * 40 + quad * 8);
    }
#pragma unroll
    for (int ot = 0; ot < 8; ot++) {
      f32x4 wyacc = (f32x4){0.f, 0.f, 0.f, 0.f};
#pragma unroll
      for (int ks = 0; ks < 8; ks++) {
        bf16x8 wv = *(const bf16x8*)(Wg + (size_t)(ot * 16 + l15) * C2n + ks * 32 + quad * 8);
        wyacc = MFMA16(yf[ks], wv, wyacc);
      }
      int o = ot * 16 + l15;
      float bv = (float)wbias[o];
#pragma unroll
      for (int r = 0; r < 4; r++)
        wyOut[((size_t)b * Nn + mw0 + rt * 16 + quad * 4 + r) * 512 + g * 128 + o] =
            (bf16_t)(wyacc[r] + bv);
    }
  }
}

// ---------- copy wy from d_out scratch into arena overlay ----------
__global__ __launch_bounds__(256) void k_copy(const float4* __restrict__ src,
                                              float4* __restrict__ dst, int n16) {
  size_t stride = (size_t)gridDim.x * blockDim.x;
  for (size_t i = (size_t)blockIdx.x * blockDim.x + threadIdx.x; i < (size_t)n16; i += stride)
    dst[i] = src[i];
}

// ---------- wy BN stats (channel-last), f64 atomics ----------
__global__ __launch_bounds__(256) void k_wy_stats(const bf16_t* __restrict__ wyBF,
                                                  double* __restrict__ stats) {
  int b = blockIdx.y;
  int m0 = blockIdx.x * 64;
  int tid = threadIdx.x;
  double s0 = 0., q0 = 0., s1 = 0., q1 = 0.;
  const bf16_t* base = wyBF + ((size_t)b * Nn + m0) * 512;
  for (int i = 0; i < 64; i++) {
    double v0 = (double)(float)base[(size_t)i * 512 + tid];
    double v1 = (double)(float)base[(size_t)i * 512 + 256 + tid];
    s0 += v0; q0 += v0 * v0; s1 += v1; q1 += v1 * v1;
  }
  atomicAdd(&stats[tid], s0);
  atomicAdd(&stats[512 + tid], q0);
  atomicAdd(&stats[256 + tid], s1);
  atomicAdd(&stats[768 + tid], q1);
}

// ---------- BN scale/shift ----------
__global__ void k_bn_st(const double* __restrict__ stats, const bf16_t* __restrict__ gamma,
                        const bf16_t* __restrict__ beta, float* __restrict__ sArr,
                        float* __restrict__ tArr, double inv_count) {
  int ch = threadIdx.x;  // 512
  double mean = stats[ch] * inv_count;
  double var = stats[512 + ch] * inv_count - mean * mean;
  double s = (double)(float)gamma[ch] / sqrt(var + (double)EPS);
  sArr[ch] = (float)s;
  tArr[ch] = (float)((double)(float)beta[ch] - mean * s);
}

// ---------- fold wy-BN into bottleneck weights ----------
__global__ __launch_bounds__(256) void k_fold(
    const bf16_t* __restrict__ par, const float* __restrict__ sW,
    const float* __restrict__ tW, bf16_t* __restrict__ bcwF, float* __restrict__ biasF) {
  int oo = blockIdx.x;
  int tid = threadIdx.x;
  const bf16_t* row = par + P_BCW + (size_t)oo * 1024;
  bf16_t* orow = bcwF + (size_t)oo * 1024;
  float part = 0.f;
  for (int c = tid; c < 512; c += 256) orow[c] = row[c];
  for (int c = 512 + tid; c < 1024; c += 256) {
    float wv = (float)row[c];
    orow[c] = (bf16_t)(wv * sW[c - 512]);
    part += wv * tW[c - 512];
  }
  __shared__ float red[256];
  red[tid] = part;
  __syncthreads();
  for (int s = 128; s > 0; s >>= 1) {
    if (tid < s) red[tid] += red[tid + s];
    __syncthreads();
  }
  if (tid == 0) biasF[oo] = (float)par[P_BCB + oo] + red[0];
}

// ---------- final GEMM: mode 0 -> f64 atomic stats; mode 1 -> normalized f32 out ----------
__global__ __launch_bounds__(256) void k_final(
    const float* __restrict__ feats, const bf16_t* __restrict__ wyBF,
    const bf16_t* __restrict__ bcwF, const float* __restrict__ biasF,
    const float* __restrict__ sO, const float* __restrict__ tO,
    double* __restrict__ stats, float* __restrict__ out, int mode) {
  __shared__ alignas(16) bf16_t xsT[64][40];
  int b = blockIdx.z;
  int tid = threadIdx.x, w = tid >> 6, lane = tid & 63;
  int l15 = lane & 15, quad = lane >> 4;
  int oo0 = blockIdx.y * 64 + w * 16;
  int n0 = blockIdx.x * 64;

  f32x4 acc[4];
#pragma unroll
  for (int j = 0; j < 4; j++) acc[j] = (f32x4){0.f, 0.f, 0.f, 0.f};

  for (int kk = 0; kk < 16; kk++) {
    int c0 = kk * 32;
    __syncthreads();
#pragma unroll
    for (int i = 0; i < 8; i++) {
      int cc = i * 4 + w;
      xsT[lane][cc] = (bf16_t)feats[((size_t)b * Cn + c0 + cc) * Nn + n0 + lane];
    }
    __syncthreads();
    bf16x8 a = *(const bf16x8*)(bcwF + (size_t)(oo0 + l15) * 1024 + c0 + quad * 8);
#pragma unroll
    for (int j = 0; j < 4; j++) {
      bf16x8 bx = *(const bf16x8*)(&xsT[j * 16 + l15][quad * 8]);
      acc[j] = MFMA16(a, bx, acc[j]);
    }
  }
  for (int kk = 0; kk < 16; kk++) {
    int c0 = kk * 32;
    bf16x8 a = *(const bf16x8*)(bcwF + (size_t)(oo0 + l15) * 1024 + 512 + c0 + quad * 8);
#pragma unroll
    for (int j = 0; j < 4; j++) {
      bf16x8 bw = *(const bf16x8*)(wyBF + ((size_t)b * Nn + n0 + j * 16 + l15) * 512 + c0 + quad * 8);
      acc[j] = MFMA16(a, bw, acc[j]);
    }
  }

  if (mode == 0) {
#pragma unroll
    for (int r = 0; r < 4; r++) {
      int row = oo0 + quad * 4 + r;
      float bv = biasF[row];
      float s = 0.f, q = 0.f;
#pragma unroll
      for (int j = 0; j < 4; j++) {
        float v = acc[j][r] + bv;
        s += v; q += v * v;
      }
      s += __shfl_xor(s, 1); q += __shfl_xor(q, 1);
      s += __shfl_xor(s, 2); q += __shfl_xor(q, 2);
      s += __shfl_xor(s, 4); q += __shfl_xor(q, 4);
      s += __shfl_xor(s, 8); q += __shfl_xor(q, 8);
      if (l15 == 0) {
        atomicAdd(&stats[row], (double)s);
        atomicAdd(&stats[512 + row], (double)q);
      }
    }
  } else {
#pragma unroll
    for (int r = 0; r < 4; r++) {
      int row = oo0 + quad * 4 + r;
      float bv = biasF[row];
      float sc = sO[row], tc = tO[row];
#pragma unroll
      for (int j = 0; j < 4; j++)
        out[((size_t)b * 512 + row) * Nn + n0 + j * 16 + l15] =
            (acc[j][r] + bv) * sc + tc;
    }
  }
}

extern "C" void kernel_launch(void* const* d_in, const int* in_sizes, int n_in,
                              void* d_out, int out_size, void* d_ws, size_t ws_size,
                              hipStream_t stream) {
  const float* feats = (const float*)d_in[0];

  char* ws = (char*)d_ws;
  bf16_t* WPAR = (bf16_t*)(ws + OFF_WPAR);
  float* biasF = (float*)(ws + OFF_BIASF);
  float* sW = (float*)(ws + OFF_SW);
  float* tW = (float*)(ws + OFF_TW2);
  float* sO = (float*)(ws + OFF_SO);
  float* tO = (float*)(ws + OFF_TO);
  double* statsWy = (double*)(ws + OFF_STATW);
  double* statsO = (double*)(ws + OFF_STATO);
  bf16_t* arena = (bf16_t*)(ws + OFF_ARENA);
  bf16_t* bcwF = (bf16_t*)(ws + OVL_BCWF);   // post-attn overlay
  bf16_t* wyCopy = (bf16_t*)(ws + OVL_WY);   // post-attn overlay
  bf16_t* wyScr = (bf16_t*)d_out;            // d_out as wy scratch during attn

  static const unsigned par_off[14] = {
      (unsigned)P_TW, (unsigned)P_TB, (unsigned)P_PW, (unsigned)P_PB,
      (unsigned)P_GW, (unsigned)P_GB, (unsigned)P_WW, (unsigned)P_WB,
      (unsigned)P_WG, (unsigned)P_WBE, (unsigned)P_BCW, (unsigned)P_BCB,
      (unsigned)P_BCG, (unsigned)P_BCBE};
  WArgs wa;
  for (int i = 0; i < 14; i++) {
    wa.src[i] = (const float*)d_in[i + 1];
    wa.n[i] = (unsigned)in_sizes[i + 1];
    wa.off[i] = par_off[i];
  }

  hipMemsetAsync(ws + OFF_STATW, 0, 16384, stream);  // statsWy + statsO

  k_wconv<<<dim3(256, 14), 256, 0, stream>>>(wa, WPAR);
  k_projKV<<<dim3(36, 4, 64), 256, 0, stream>>>(feats, WPAR, arena);
  k_attn_wy<<<dim3(18, 32), 256, 0, stream>>>(feats, arena, WPAR, wyScr);
  k_copy<<<1152, 256, 0, stream>>>((const float4*)wyScr, (float4*)wyCopy, 1179648);
  k_wy_stats<<<dim3(36, 8), 256, 0, stream>>>(wyCopy, statsWy);
  k_bn_st<<<1, 512, 0, stream>>>(statsWy, WPAR + P_WG, WPAR + P_WBE, sW, tW, 1.0 / 18432.0);
  k_fold<<<512, 256, 0, stream>>>(WPAR, sW, tW, bcwF, biasF);
  k_final<<<dim3(36, 8, 8), 256, 0, stream>>>(feats, wyCopy, bcwF, biasF, sO, tO, statsO,
                                              (float*)d_out, 0);
  k_bn_st<<<1, 512, 0, stream>>>(statsO, WPAR + P_BCG, WPAR + P_BCBE, sO, tO, 1.0 / 18432.0);
  k_final<<<dim3(36, 8, 8), 256, 0, stream>>>(feats, wyCopy, bcwF, biasF, sO, tO, statsO,
                                              (float*)d_out, 1);
}